// Round 4
// baseline (461.288 us; speedup 1.0000x reference)
//
#include <hip/hip_runtime.h>

typedef __bf16 bf16x8 __attribute__((ext_vector_type(8)));
typedef float floatx4 __attribute__((ext_vector_type(4)));

__device__ __forceinline__ unsigned short f2bf(float x) {
  union { float f; unsigned u; } v; v.f = x;
  unsigned u = v.u;
  unsigned r = (u + 0x7FFFu + ((u >> 16) & 1u)) >> 16;
  return (unsigned short)r;
}
__device__ __forceinline__ float bf2f(unsigned short x) {
  union { unsigned u; float f; } v; v.u = ((unsigned)x) << 16;
  return v.f;
}
__device__ __forceinline__ float fast_rcp(float x) {
#if defined(__has_builtin) && __has_builtin(__builtin_amdgcn_rcpf)
  return __builtin_amdgcn_rcpf(x);
#else
  return 1.0f / x;
#endif
}
__device__ __forceinline__ float fast_rsq(float x) {
#if defined(__has_builtin) && __has_builtin(__builtin_amdgcn_rsqf)
  return __builtin_amdgcn_rsqf(x);
#else
  return 1.0f / sqrtf(x);
#endif
}

// ---- async global->LDS staging (16B/lane, wave-uniform LDS base) ----
__device__ __forceinline__ void stage16(const unsigned short* __restrict__ g,
                                        unsigned short* s, int lane) {
#if defined(__has_builtin) && __has_builtin(__builtin_amdgcn_global_load_lds)
  __builtin_amdgcn_global_load_lds((const __attribute__((address_space(1))) void*)g,
                                   (__attribute__((address_space(3))) void*)s,
                                   16, 0, 0);
#else
  *(uint4*)(s + (size_t)lane * 8) = *(const uint4*)g;
#endif
}

// ---- fp32 -> bf16 elementwise convert (float4 loads) ----
__global__ void cvt_bf16(const float* __restrict__ in, unsigned short* __restrict__ out, int n4) {
  int i = blockIdx.x * 256 + threadIdx.x;
  if (i >= n4) return;
  const float4 v = ((const float4*)in)[i];
  ushort4 o;
  o.x = f2bf(v.x); o.y = f2bf(v.y); o.z = f2bf(v.z); o.w = f2bf(v.w);
  ((ushort4*)out)[i] = o;
}

// ============================================================================
// 256x256 8-phase bf16 GEMM, C[m,n] = sum_k A[m,k]B[n,k]+bias[n]
//
// Geometry: BM=BN=256, BK=64, 512 thr = 8 waves. Wave w owns four 64x32 output
// blocks, one per C-quadrant (mh,nh). Phase (mh,nh) reads ONLY A_mh / B_nh.
// LDS: As[2][256][64], Bs[2][256][64] bf16 = 128 KiB, tile t -> buf t&1.
// Swizzle: 16B k-group g of row R stored at slot g^(R&7); staging pre-swizzles
// the GLOBAL source, LDS dest stays linear (global_load_lds rule).
//
// v4: DERIVED PER-PHASE WAITS. Stage placement (tile t): p1->A1(t+1),
// p2->A0(t+2), p3->B0(t+2), p4->B1(t+2) (2 loads each). Steady-state
// outstanding entering p1 = 10: [B1t,A1t,A0t+1,B0t+1,B1t+1] (pairs).
// Phase shape: { ds_reads ; stage ; MFMA(counted lgkm by compiler) ;
//                [vmcnt(W)] ; s_barrier }.
//   p1-end W=10 (retире B1t -> p2 reads, issued 6 phases prior)
//   p2-end W=10 (retire A1t -> p3 reads, issued 6 phases prior)
//   p3-end none (p4 has no ds_reads)
//   p4-end W=10 (retire A0,B0(t+1) -> next p1 reads, issued 7 phases prior)
// Every vmcnt is followed by a barrier (cross-wave publication). Last pair
// peeled with exact counts: T: (10,8,-,4); T+1: (2,0,-,-). The asm "memory"
// clobbers fence ds_reads/stages/epilogue loads against reordering across
// counts. NO spills allowed (scratch vmem would corrupt vmcnt counts).
// ============================================================================
#define LDSE (256 * 64)

#define VMW_(n) asm volatile("s_waitcnt vmcnt(" #n ")" ::: "memory")
#define VMW(n) VMW_(n)
#define BAR() __builtin_amdgcn_s_barrier()

#define RD_A(b, mh) {                                                          \
  _Pragma("unroll") for (int ii = 0; ii < 4; ++ii) {                           \
    _Pragma("unroll") for (int s = 0; s < 2; ++s) {                            \
      af[ii][s] = *(const bf16x8*)(rA + (b) * LDSE +                           \
                                   ((mh) * 128 + ii * 16) * 64 +               \
                                   (((s << 2) | quad) ^ key) * 8);             \
    } } }

#define RD_B(b, nh, dst) {                                                     \
  _Pragma("unroll") for (int jj = 0; jj < 2; ++jj) {                           \
    _Pragma("unroll") for (int s = 0; s < 2; ++s) {                            \
      dst[jj][s] = *(const bf16x8*)(rB + (b) * LDSE +                          \
                                    ((nh) * 128 + jj * 16) * 64 +              \
                                    (((s << 2) | quad) ^ key) * 8);            \
    } } }

#define STAGE_A(b, mh, t) {                                                    \
  stage16(gA + (size_t)((mh) * 128) * K + (size_t)(t) * 64,                    \
          sAw + (b) * LDSE + ((mh) * 128) * 64, lane);                         \
  stage16(gA + (size_t)((mh) * 128 + 8) * K + (size_t)(t) * 64,                \
          sAw + (b) * LDSE + ((mh) * 128 + 8) * 64, lane); }

#define STAGE_B(b, nh, t) {                                                    \
  stage16(gB + (size_t)((nh) * 128) * K + (size_t)(t) * 64,                    \
          sBw + (b) * LDSE + ((nh) * 128) * 64, lane);                         \
  stage16(gB + (size_t)((nh) * 128 + 8) * K + (size_t)(t) * 64,                \
          sBw + (b) * LDSE + ((nh) * 128 + 8) * 64, lane); }

#define MFMA_PH(mh, nh, bfx) {                                                 \
  __builtin_amdgcn_s_setprio(1);                                               \
  _Pragma("unroll") for (int s = 0; s < 2; ++s) {                              \
    _Pragma("unroll") for (int ii = 0; ii < 4; ++ii) {                         \
      _Pragma("unroll") for (int jj = 0; jj < 2; ++jj) {                       \
        acc[mh][nh][ii][jj] = __builtin_amdgcn_mfma_f32_16x16x32_bf16(         \
            af[ii][s], bfx[jj][s], acc[mh][nh][ii][jj], 0, 0, 0);              \
      } } }                                                                    \
  __builtin_amdgcn_s_setprio(0); }

// steady-state tile: full staging, waits (10,10,-,10)
#define TILE_ST(b, t) {                                                        \
  RD_B(b, 0, bf0); RD_A(b, 0); STAGE_A((b) ^ 1, 1, (t) + 1);                   \
  MFMA_PH(0, 0, bf0); VMW(10); BAR();                                          \
  RD_B(b, 1, bf1); STAGE_A(b, 0, (t) + 2);                                     \
  MFMA_PH(0, 1, bf1); VMW(10); BAR();                                          \
  RD_A(b, 1); STAGE_B(b, 0, (t) + 2);                                          \
  MFMA_PH(1, 1, bf1); BAR();                                                   \
  STAGE_B(b, 1, (t) + 2);                                                      \
  MFMA_PH(1, 0, bf0); VMW(10); BAR(); }

template <int OUT_BF16>
__global__ __launch_bounds__(512, 2) void gemm8p(const unsigned short* __restrict__ A,
                                                 const unsigned short* __restrict__ B,
                                                 const float* __restrict__ bias,
                                                 void* __restrict__ Cv,
                                                 int M, int N, int K) {
  __shared__ unsigned short As[2 * 256 * 64];  // 64 KB
  __shared__ unsigned short Bs[2 * 256 * 64];  // 64 KB
  const int tid = threadIdx.x;
  const int w = tid >> 6;
  const int lane = tid & 63;

  const int NT = N >> 8;
  const int id = blockIdx.x;
  const int x = id & 7;
  const int g = id >> 3;
  const int nt_ = g % NT;
  const int mt = x + 8 * (g / NT);
  const int bm = mt * 256, bn = nt_ * 256;

  const int row16 = lane & 15, quad = lane >> 4, key = lane & 7;
  const int l8 = lane >> 3, lk = lane & 7;
  const int swz = (lk ^ l8) * 8;  // pre-swizzled global k-offset (elements)

  const unsigned short* gA = A + (size_t)(bm + 16 * w + l8) * K + swz;
  const unsigned short* gB = B + (size_t)(bn + 16 * w + l8) * K + swz;
  unsigned short* sAw = As + (16 * w) * 64;
  unsigned short* sBw = Bs + (16 * w) * 64;

  const unsigned short* rA = As + ((w >> 2) * 64 + row16) * 64;
  const unsigned short* rB = Bs + ((w & 3) * 32 + row16) * 64;

  floatx4 acc[2][2][4][2] = {};   // [mh][nh][ii][jj]
  bf16x8 af[4][2], bf0[2][2], bf1[2][2];

  // prologue: issue in the steady-state order [A0,B0,B1,A1](0), [A0,B0,B1](1)
  STAGE_A(0, 0, 0); STAGE_B(0, 0, 0); STAGE_B(0, 1, 0); STAGE_A(0, 1, 0);
  STAGE_A(1, 0, 1); STAGE_B(1, 0, 1); STAGE_B(1, 1, 1);
  VMW(10);  // retire A0(0),B0(0) for p1 reads
  BAR();

  const int npair = K >> 7;  // two 64-wide K-tiles per iteration
  for (int it = 0; it < npair - 1; ++it) {
    const int t0 = it * 2;
    TILE_ST(0, t0);
    TILE_ST(1, t0 + 1);
  }

  // peeled last pair: T = 2*npair-2 (buf0), T+1 (buf1)
  {
    const int T = 2 * npair - 2;
    // TILE(0,T): stage only A1(T+1); waits (10, 8, -, 4)
    RD_B(0, 0, bf0); RD_A(0, 0); STAGE_A(1, 1, T + 1);
    MFMA_PH(0, 0, bf0); VMW(10); BAR();
    RD_B(0, 1, bf1);
    MFMA_PH(0, 1, bf1); VMW(8); BAR();
    RD_A(0, 1);
    MFMA_PH(1, 1, bf1); BAR();
    MFMA_PH(1, 0, bf0); VMW(4); BAR();
    // TILE(1,T+1): no stages; waits (2, 0, -, -)
    RD_B(1, 0, bf0); RD_A(1, 0);
    MFMA_PH(0, 0, bf0); VMW(2); BAR();
    RD_B(1, 1, bf1);
    MFMA_PH(0, 1, bf1); VMW(0); BAR();
    RD_A(1, 1);
    MFMA_PH(1, 1, bf1); BAR();
    MFMA_PH(1, 0, bf0);
  }

  // epilogue: C/D layout col=lane&15, row=quad*4+reg
#pragma unroll
  for (int nh = 0; nh < 2; ++nh)
#pragma unroll
    for (int jj = 0; jj < 2; ++jj) {
      const int gcol = bn + nh * 128 + (w & 3) * 32 + jj * 16 + row16;
      const float bb = bias ? bias[gcol] : 0.0f;
#pragma unroll
      for (int mh = 0; mh < 2; ++mh)
#pragma unroll
        for (int ii = 0; ii < 4; ++ii) {
          const int grow = bm + mh * 128 + (w >> 2) * 64 + ii * 16 + quad * 4;
#pragma unroll
          for (int r = 0; r < 4; ++r) {
            float v = acc[mh][nh][ii][jj][r] + bb;
            if (OUT_BF16)
              ((unsigned short*)Cv)[(size_t)(grow + r) * N + gcol] = f2bf(v);
            else
              ((float*)Cv)[(size_t)(grow + r) * N + gcol] = v;
          }
        }
    }
}

// ---- scan pass 1: per-chunk partial sums (128 chunks x 32 rows) ----
__global__ void scan_partial(const unsigned short* __restrict__ proj, float* __restrict__ partial) {
  const int t = blockIdx.x, chunk = blockIdx.y, b = blockIdx.z;
  const int c4 = threadIdx.x * 4;
  const unsigned short* p =
      proj + ((size_t)t * 4 + b) * 4096 * 1024 + (size_t)chunk * 32 * 1024 + c4;
  float4 s = {0.f, 0.f, 0.f, 0.f};
  for (int i = 0; i < 32; i++) {
    const ushort4 v = *(const ushort4*)(p + (size_t)i * 1024);
    s.x += bf2f(v.x); s.y += bf2f(v.y); s.z += bf2f(v.z); s.w += bf2f(v.w);
  }
  *(float4*)(partial + ((size_t)(t * 4 + b) * 128 + chunk) * 1024 + c4) = s;
}

// ---- scan pass 2: prefix + running mean + head L2-norm + pack ----
__global__ void scan_apply(const unsigned short* __restrict__ proj,
                           const float* __restrict__ partial,
                           unsigned short* __restrict__ qkn) {
  const int t = blockIdx.x, chunk = blockIdx.y, b = blockIdx.z;
  const int c4 = threadIdx.x * 4;
  const float* pp = partial + (size_t)(t * 4 + b) * 128 * 1024 + c4;
  float4 run = {0.f, 0.f, 0.f, 0.f};
  for (int j = 0; j < chunk; j++) {
    const float4 v = *(const float4*)(pp + (size_t)j * 1024);
    run.x += v.x; run.y += v.y; run.z += v.z; run.w += v.w;
  }
  const unsigned short* p =
      proj + ((size_t)t * 4 + b) * 4096 * 1024 + (size_t)chunk * 32 * 1024 + c4;
  unsigned short* o = qkn + (size_t)b * 4096 * 2048 + (size_t)chunk * 32 * 2048 + t * 1024 + c4;
  for (int i = 0; i < 32; i++) {
    const ushort4 v = *(const ushort4*)(p + (size_t)i * 1024);
    run.x += bf2f(v.x); run.y += bf2f(v.y); run.z += bf2f(v.z); run.w += bf2f(v.w);
    const int s = chunk * 32 + i;
    const float inv = fast_rcp((float)(s + 1));
    const float a0 = run.x * inv, a1 = run.y * inv, a2 = run.z * inv, a3 = run.w * inv;
    float sq = a0 * a0 + a1 * a1 + a2 * a2 + a3 * a3;
    sq += __shfl_xor(sq, 8);
    sq += __shfl_xor(sq, 4);
    sq += __shfl_xor(sq, 2);
    sq += __shfl_xor(sq, 1);
    const float sc = fast_rsq(fmaxf(sq, 1e-24f));
    ushort4 ov;
    ov.x = f2bf(a0 * sc); ov.y = f2bf(a1 * sc); ov.z = f2bf(a2 * sc); ov.w = f2bf(a3 * sc);
    *(ushort4*)(o + (size_t)i * 2048) = ov;
  }
}

// ---- tiny precomputes: A[t][h] = W(e/r)[h] @ Wc[:, t*32:+32]^T  (64x64 each) ----
__global__ void make_A(const float* __restrict__ We, const float* __restrict__ Wr,
                       const float* __restrict__ Wc, float* __restrict__ Asm) {
  const int t = blockIdx.x >> 4, h = blockIdx.x & 15;
  const float* W = (t ? Wr : We) + (size_t)h * 64 * 32;
  for (int e = threadIdx.x; e < 4096; e += 256) {
    const int d = e >> 6, dk = e & 63;
    float s = 0.f;
    for (int r = 0; r < 32; r++) s += W[d * 32 + r] * Wc[dk * 64 + t * 32 + r];
    Asm[(size_t)blockIdx.x * 4096 + e] = s;
  }
}

// ---- Gt[f][t*1024+h*64+d] = sum_dk A[t][h][d][dk] * Wo[f][h*64+dk] ----
__global__ __launch_bounds__(256) void make_G(const float* __restrict__ Asm,
                                              const float* __restrict__ Wo,
                                              unsigned short* __restrict__ Gt) {
  __shared__ float At[64 * 65];    // At[dk][d], padded
  __shared__ float WoSh[64 * 64];  // WoSh[fl][dk]
  const int th = blockIdx.x, t = th >> 4, h = th & 15;
  const int f0 = blockIdx.y * 64;
  const int tid = threadIdx.x;
  for (int e = tid; e < 4096; e += 256) {
    const int d = e >> 6, dk = e & 63;
    At[dk * 65 + d] = Asm[(size_t)th * 4096 + e];
  }
  for (int e = tid; e < 4096; e += 256) {
    const int fl = e >> 6, dk = e & 63;
    WoSh[e] = Wo[(size_t)(f0 + fl) * 1024 + h * 64 + dk];
  }
  __syncthreads();
  const int d = tid & 63;
  const int fsub = tid >> 6;  // 0..3
#pragma unroll 4
  for (int it = 0; it < 16; ++it) {
    const int fl = it * 4 + fsub;
    float s = 0.f;
#pragma unroll
    for (int dk4 = 0; dk4 < 16; ++dk4) {
      const float4 wv = *(const float4*)&WoSh[fl * 64 + dk4 * 4];
      s += At[(dk4 * 4 + 0) * 65 + d] * wv.x + At[(dk4 * 4 + 1) * 65 + d] * wv.y +
           At[(dk4 * 4 + 2) * 65 + d] * wv.z + At[(dk4 * 4 + 3) * 65 + d] * wv.w;
    }
    Gt[(size_t)(f0 + fl) * 2048 + t * 1024 + h * 64 + d] = f2bf(s);
  }
}

// ---- c0[f] = bo[f] + sum_j bc[j&63]*Wo[f][j]; one wave per f ----
__global__ void make_c0(const float* __restrict__ bc, const float* __restrict__ bo,
                        const float* __restrict__ Wo, float* __restrict__ c0) {
  const int f = blockIdx.x * 4 + (threadIdx.x >> 6);
  const int lane = threadIdx.x & 63;
  const float bcl = bc[lane];
  float s = 0.f;
  for (int j = lane; j < 1024; j += 64) s += bcl * Wo[(size_t)f * 1024 + j];
#pragma unroll
  for (int off = 32; off; off >>= 1) s += __shfl_xor(s, off);
  if (lane == 0) c0[f] = s + bo[f];
}

extern "C" void kernel_launch(void* const* d_in, const int* in_sizes, int n_in,
                              void* d_out, int out_size, void* d_ws, size_t ws_size,
                              hipStream_t stream) {
  const float* query = (const float*)d_in[0];
  const float* key_  = (const float*)d_in[1];
  const float* Wq = (const float*)d_in[4];
  const float* bq = (const float*)d_in[5];
  const float* Wk = (const float*)d_in[6];
  const float* bk = (const float*)d_in[7];
  const float* We = (const float*)d_in[10];
  const float* Wr = (const float*)d_in[11];
  const float* Wc = (const float*)d_in[13];
  const float* bc = (const float*)d_in[14];
  const float* Wo = (const float*)d_in[15];
  const float* bo = (const float*)d_in[16];

  // ws layout (max 76.1 MB)
  char* ws = (char*)d_ws;
  unsigned short* qkbf = (unsigned short*)ws;               // 67MB: q/k bf16, later QKn (16384x2048)
  unsigned short* Wbf  = (unsigned short*)(ws + 67108864);  // 4MB: Wq,Wk bf16
  unsigned short* Gt   = (unsigned short*)(ws + 71303168);  // 4MB: G^T (1024x2048 bf16)
  float* partial       = (float*)(ws + 71303168);           // 4MB, OVERLAYS Gt (dead before make_G)
  float* Asm           = (float*)(ws + 75497472);           // 512KB
  float* c0            = (float*)(ws + 76021760);           // 4KB

  unsigned short* proj = (unsigned short*)d_out;  // d_out as scratch for bf16 projections

  // 1) fp32 -> bf16
  cvt_bf16<<<16384, 256, 0, stream>>>(query, qkbf, 4194304);
  cvt_bf16<<<16384, 256, 0, stream>>>(key_, qkbf + 16777216, 4194304);
  cvt_bf16<<<1024, 256, 0, stream>>>(Wq, Wbf, 262144);
  cvt_bf16<<<1024, 256, 0, stream>>>(Wk, Wbf + 1048576, 262144);

  // 2) q/k projections (M=16384, N=1024, K=1024) -> bf16 proj in d_out
  gemm8p<1><<<256, 512, 0, stream>>>(qkbf, Wbf, bq, proj, 16384, 1024, 1024);
  gemm8p<1><<<256, 512, 0, stream>>>(qkbf + 16777216, Wbf + 1048576, bk,
                                     proj + 16777216, 16384, 1024, 1024);

  // 3) causal running mean + l2norm + pack into QKn
  scan_partial<<<dim3(2, 128, 4), 256, 0, stream>>>(proj, partial);
  scan_apply<<<dim3(2, 128, 4), 256, 0, stream>>>(proj, partial, qkbf);

  // 4) fold We/Wr/Wc/Wo into G (after scan: partial dead, Gt region free)
  make_A<<<32, 256, 0, stream>>>(We, Wr, Wc, Asm);
  make_G<<<dim3(32, 16), 256, 0, stream>>>(Asm, Wo, Gt);
  make_c0<<<256, 256, 0, stream>>>(bc, bo, Wo, c0);

  // 5) out = QKn @ Gt^T + c0  (M=16384, N=1024, K=2048), fp32 out
  gemm8p<0><<<256, 512, 0, stream>>>(qkbf, Gt, c0, (float*)d_out, 16384, 1024, 2048);
}

// Round 5
// 446.904 us; speedup vs baseline: 1.0322x; 1.0322x over previous
//
#include <hip/hip_runtime.h>

typedef __bf16 bf16x8 __attribute__((ext_vector_type(8)));
typedef float floatx4 __attribute__((ext_vector_type(4)));

__device__ __forceinline__ unsigned short f2bf(float x) {
  union { float f; unsigned u; } v; v.f = x;
  unsigned u = v.u;
  unsigned r = (u + 0x7FFFu + ((u >> 16) & 1u)) >> 16;
  return (unsigned short)r;
}
__device__ __forceinline__ float bf2f(unsigned short x) {
  union { unsigned u; float f; } v; v.u = ((unsigned)x) << 16;
  return v.f;
}
__device__ __forceinline__ float fast_rcp(float x) {
#if defined(__has_builtin) && __has_builtin(__builtin_amdgcn_rcpf)
  return __builtin_amdgcn_rcpf(x);
#else
  return 1.0f / x;
#endif
}
__device__ __forceinline__ float fast_rsq(float x) {
#if defined(__has_builtin) && __has_builtin(__builtin_amdgcn_rsqf)
  return __builtin_amdgcn_rsqf(x);
#else
  return 1.0f / sqrtf(x);
#endif
}

// ---- async global->LDS staging (16B/lane, wave-uniform LDS base) ----
__device__ __forceinline__ void stage16(const unsigned short* __restrict__ g,
                                        unsigned short* s, int lane) {
#if defined(__has_builtin) && __has_builtin(__builtin_amdgcn_global_load_lds)
  __builtin_amdgcn_global_load_lds((const __attribute__((address_space(1))) void*)g,
                                   (__attribute__((address_space(3))) void*)s,
                                   16, 0, 0);
#else
  *(uint4*)(s + (size_t)lane * 8) = *(const uint4*)g;
#endif
}

// ---- fp32 -> bf16 elementwise convert (float4 loads) ----
__global__ void cvt_bf16(const float* __restrict__ in, unsigned short* __restrict__ out, int n4) {
  int i = blockIdx.x * 256 + threadIdx.x;
  if (i >= n4) return;
  const float4 v = ((const float4*)in)[i];
  ushort4 o;
  o.x = f2bf(v.x); o.y = f2bf(v.y); o.z = f2bf(v.z); o.w = f2bf(v.w);
  ((ushort4*)out)[i] = o;
}

// ============================================================================
// 256x256 bf16 GEMM, ONE barrier per K-tile. C[m,n]=sum_k A[m,k]B[n,k]+bias[n]
//
// Geometry: BM=BN=256, BK=64, 512 thr = 8 waves. Wave w owns four 64x32 output
// blocks, one per C-quadrant (mh,nh).
// LDS: As[2][256][64], Bs[2][256][64] bf16 = 128 KiB, tile t -> buf t&1.
// Swizzle: 16B k-group g of row R stored at slot g^(R&7); staging pre-swizzles
// the GLOBAL source, LDS dest stays linear (global_load_lds rule).
//
// v5: PER-TILE SYNC ONLY. R2-R4 showed the per-phase {16-MFMA cluster ->
// barrier} shape leaves the matrix pipe drained at every barrier (a wave
// reaches the barrier only after issuing its last MFMA ~620cy), so each
// phase paid read-latency + MFMA + skew SERIALLY (5560 cyc/K-tile measured,
// 36% MfmaUtil; identical for 2-barrier, 1-barrier, counted-vmcnt variants).
// Now: per tile t = { stage ALL of t+1 -> buf^1 (8 calls, issued at top,
// ~2500cy in flight) ; 24 ds_reads + 64 MFMA freely pipelined by compiler
// (counted lgkm per consumer) ; vmcnt(0) (free: retires own stages issued
// 2500cy prior; spill-safe) ; s_barrier }. Read-latency bubble paid once
// per tile, not 4x. Safety: a wave's last MFMA consumes its last ds_read
// (in-order lgkm) => reads complete before barrier arrival; per-wave
// vmcnt(0) pre-barrier => after barrier all waves' stages are visible;
// clean double-buffer => no intra-tile hazards.
//
// halfM/B2/bias2: merged dispatch support — blocks with bm>=halfM use B2/bias2
// (lets q-proj and k-proj run as one 512-block launch).
// ============================================================================
#define LDSE (256 * 64)
#define BAR() __builtin_amdgcn_s_barrier()

#define RD_A(b, mh) {                                                          \
  _Pragma("unroll") for (int ii = 0; ii < 4; ++ii) {                           \
    _Pragma("unroll") for (int s = 0; s < 2; ++s) {                            \
      af[ii][s] = *(const bf16x8*)(rA + (b) * LDSE +                           \
                                   ((mh) * 128 + ii * 16) * 64 +               \
                                   (((s << 2) | quad) ^ key) * 8);             \
    } } }

#define RD_B(b, nh, dst) {                                                     \
  _Pragma("unroll") for (int jj = 0; jj < 2; ++jj) {                           \
    _Pragma("unroll") for (int s = 0; s < 2; ++s) {                            \
      dst[jj][s] = *(const bf16x8*)(rB + (b) * LDSE +                          \
                                    ((nh) * 128 + jj * 16) * 64 +              \
                                    (((s << 2) | quad) ^ key) * 8);            \
    } } }

#define STAGE_A(b, mh, t) {                                                    \
  stage16(gA + (size_t)((mh) * 128) * K + (size_t)(t) * 64,                    \
          sAw + (b) * LDSE + ((mh) * 128) * 64, lane);                         \
  stage16(gA + (size_t)((mh) * 128 + 8) * K + (size_t)(t) * 64,                \
          sAw + (b) * LDSE + ((mh) * 128 + 8) * 64, lane); }

#define STAGE_B(b, nh, t) {                                                    \
  stage16(gB + (size_t)((nh) * 128) * K + (size_t)(t) * 64,                    \
          sBw + (b) * LDSE + ((nh) * 128) * 64, lane);                         \
  stage16(gB + (size_t)((nh) * 128 + 8) * K + (size_t)(t) * 64,                \
          sBw + (b) * LDSE + ((nh) * 128 + 8) * 64, lane); }

#define MFMA_PH(mh, nh, bfx) {                                                 \
  __builtin_amdgcn_s_setprio(1);                                               \
  _Pragma("unroll") for (int s = 0; s < 2; ++s) {                              \
    _Pragma("unroll") for (int ii = 0; ii < 4; ++ii) {                         \
      _Pragma("unroll") for (int jj = 0; jj < 2; ++jj) {                       \
        acc[mh][nh][ii][jj] = __builtin_amdgcn_mfma_f32_16x16x32_bf16(         \
            af[ii][s], bfx[jj][s], acc[mh][nh][ii][jj], 0, 0, 0);              \
      } } }                                                                    \
  __builtin_amdgcn_s_setprio(0); }

// one K-tile: stage t+1 at top (S), compute t, single sync (Y)
#define TILE5(b, t, S, Y) {                                                    \
  if (S) { STAGE_A((b) ^ 1, 0, (t) + 1); STAGE_B((b) ^ 1, 0, (t) + 1);         \
           STAGE_B((b) ^ 1, 1, (t) + 1); STAGE_A((b) ^ 1, 1, (t) + 1); }       \
  RD_B(b, 0, bf0); RD_A(b, 0);                                                 \
  MFMA_PH(0, 0, bf0);                                                          \
  RD_B(b, 1, bf1);                                                             \
  MFMA_PH(0, 1, bf1);                                                          \
  RD_A(b, 1);                                                                  \
  MFMA_PH(1, 1, bf1);                                                          \
  MFMA_PH(1, 0, bf0);                                                          \
  if (Y) { asm volatile("s_waitcnt vmcnt(0)" ::: "memory"); BAR(); } }

template <int OUT_BF16>
__global__ __launch_bounds__(512, 2) void gemm8p(const unsigned short* __restrict__ A,
                                                 const unsigned short* __restrict__ B,
                                                 const unsigned short* __restrict__ B2,
                                                 const float* __restrict__ bias,
                                                 const float* __restrict__ bias2,
                                                 void* __restrict__ Cv,
                                                 int M, int N, int K, int halfM) {
  __shared__ unsigned short As[2 * 256 * 64];  // 64 KB
  __shared__ unsigned short Bs[2 * 256 * 64];  // 64 KB
  const int tid = threadIdx.x;
  const int w = tid >> 6;
  const int lane = tid & 63;

  const int NT = N >> 8;
  const int id = blockIdx.x;
  const int x = id & 7;
  const int g = id >> 3;
  const int nt_ = g % NT;
  const int mt = x + 8 * (g / NT);
  const int bm = mt * 256, bn = nt_ * 256;

  const unsigned short* Bp = (bm >= halfM) ? B2 : B;
  const float* biasp = (bm >= halfM) ? bias2 : bias;

  const int row16 = lane & 15, quad = lane >> 4, key = lane & 7;
  const int l8 = lane >> 3, lk = lane & 7;
  const int swz = (lk ^ l8) * 8;  // pre-swizzled global k-offset (elements)

  const unsigned short* gA = A + (size_t)(bm + 16 * w + l8) * K + swz;
  const unsigned short* gB = Bp + (size_t)(bn + 16 * w + l8) * K + swz;
  unsigned short* sAw = As + (16 * w) * 64;
  unsigned short* sBw = Bs + (16 * w) * 64;

  const unsigned short* rA = As + ((w >> 2) * 64 + row16) * 64;
  const unsigned short* rB = Bs + ((w & 3) * 32 + row16) * 64;

  floatx4 acc[2][2][4][2] = {};   // [mh][nh][ii][jj]
  bf16x8 af[4][2], bf0[2][2], bf1[2][2];

  // prologue: stage tile 0, retire, publish
  STAGE_A(0, 0, 0); STAGE_B(0, 0, 0); STAGE_B(0, 1, 0); STAGE_A(0, 1, 0);
  asm volatile("s_waitcnt vmcnt(0)" ::: "memory");
  BAR();

  const int npair = K >> 7;  // two 64-wide K-tiles per iteration
  for (int it = 0; it < npair - 1; ++it) {
    TILE5(0, 2 * it, true, true);
    TILE5(1, 2 * it + 1, true, true);
  }
  TILE5(0, 2 * npair - 2, true, true);
  TILE5(1, 2 * npair - 1, false, false);  // last tile: no stage, no sync

  // epilogue: C/D layout col=lane&15, row=quad*4+reg
#pragma unroll
  for (int nh = 0; nh < 2; ++nh)
#pragma unroll
    for (int jj = 0; jj < 2; ++jj) {
      const int gcol = bn + nh * 128 + (w & 3) * 32 + jj * 16 + row16;
      const float bb = biasp ? biasp[gcol] : 0.0f;
#pragma unroll
      for (int mh = 0; mh < 2; ++mh)
#pragma unroll
        for (int ii = 0; ii < 4; ++ii) {
          const int grow = bm + mh * 128 + (w >> 2) * 64 + ii * 16 + quad * 4;
#pragma unroll
          for (int r = 0; r < 4; ++r) {
            float v = acc[mh][nh][ii][jj][r] + bb;
            if (OUT_BF16)
              ((unsigned short*)Cv)[(size_t)(grow + r) * N + gcol] = f2bf(v);
            else
              ((float*)Cv)[(size_t)(grow + r) * N + gcol] = v;
          }
        }
    }
}

// ---- scan pass 1: per-chunk partial sums (64 chunks x 64 rows) ----
__global__ void scan_partial(const unsigned short* __restrict__ proj, float* __restrict__ partial) {
  const int t = blockIdx.x, chunk = blockIdx.y, b = blockIdx.z;
  const int c4 = threadIdx.x * 4;
  const unsigned short* p =
      proj + ((size_t)t * 4 + b) * 4096 * 1024 + (size_t)chunk * 64 * 1024 + c4;
  float4 s = {0.f, 0.f, 0.f, 0.f};
  for (int i = 0; i < 64; i++) {
    const ushort4 v = *(const ushort4*)(p + (size_t)i * 1024);
    s.x += bf2f(v.x); s.y += bf2f(v.y); s.z += bf2f(v.z); s.w += bf2f(v.w);
  }
  *(float4*)(partial + ((size_t)(t * 4 + b) * 64 + chunk) * 1024 + c4) = s;
}

// ---- scan pass 2: prefix + running mean + head L2-norm + pack ----
__global__ void scan_apply(const unsigned short* __restrict__ proj,
                           const float* __restrict__ partial,
                           unsigned short* __restrict__ qkn) {
  const int t = blockIdx.x, chunk = blockIdx.y, b = blockIdx.z;
  const int c4 = threadIdx.x * 4;
  const float* pp = partial + (size_t)(t * 4 + b) * 64 * 1024 + c4;
  float4 run = {0.f, 0.f, 0.f, 0.f};
  for (int j = 0; j < chunk; j++) {
    const float4 v = *(const float4*)(pp + (size_t)j * 1024);
    run.x += v.x; run.y += v.y; run.z += v.z; run.w += v.w;
  }
  const unsigned short* p =
      proj + ((size_t)t * 4 + b) * 4096 * 1024 + (size_t)chunk * 64 * 1024 + c4;
  unsigned short* o = qkn + (size_t)b * 4096 * 2048 + (size_t)chunk * 64 * 2048 + t * 1024 + c4;
  for (int i = 0; i < 64; i++) {
    const ushort4 v = *(const ushort4*)(p + (size_t)i * 1024);
    run.x += bf2f(v.x); run.y += bf2f(v.y); run.z += bf2f(v.z); run.w += bf2f(v.w);
    const int s = chunk * 64 + i;
    const float inv = fast_rcp((float)(s + 1));
    const float a0 = run.x * inv, a1 = run.y * inv, a2 = run.z * inv, a3 = run.w * inv;
    float sq = a0 * a0 + a1 * a1 + a2 * a2 + a3 * a3;
    sq += __shfl_xor(sq, 8);
    sq += __shfl_xor(sq, 4);
    sq += __shfl_xor(sq, 2);
    sq += __shfl_xor(sq, 1);
    const float sc = fast_rsq(fmaxf(sq, 1e-24f));
    ushort4 ov;
    ov.x = f2bf(a0 * sc); ov.y = f2bf(a1 * sc); ov.z = f2bf(a2 * sc); ov.w = f2bf(a3 * sc);
    *(ushort4*)(o + (size_t)i * 2048) = ov;
  }
}

// ---- tiny precomputes: A[t][h] = W(e/r)[h] @ Wc[:, t*32:+32]^T  (64x64 each) ----
__global__ void make_A(const float* __restrict__ We, const float* __restrict__ Wr,
                       const float* __restrict__ Wc, float* __restrict__ Asm) {
  const int t = blockIdx.x >> 4, h = blockIdx.x & 15;
  const float* W = (t ? Wr : We) + (size_t)h * 64 * 32;
  for (int e = threadIdx.x; e < 4096; e += 256) {
    const int d = e >> 6, dk = e & 63;
    float s = 0.f;
    for (int r = 0; r < 32; r++) s += W[d * 32 + r] * Wc[dk * 64 + t * 32 + r];
    Asm[(size_t)blockIdx.x * 4096 + e] = s;
  }
}

// ---- Gt[f][t*1024+h*64+d] = sum_dk A[t][h][d][dk] * Wo[f][h*64+dk] ----
__global__ __launch_bounds__(256) void make_G(const float* __restrict__ Asm,
                                              const float* __restrict__ Wo,
                                              unsigned short* __restrict__ Gt) {
  __shared__ float At[64 * 65];    // At[dk][d], padded
  __shared__ float WoSh[64 * 64];  // WoSh[fl][dk]
  const int th = blockIdx.x, t = th >> 4, h = th & 15;
  const int f0 = blockIdx.y * 64;
  const int tid = threadIdx.x;
  for (int e = tid; e < 4096; e += 256) {
    const int d = e >> 6, dk = e & 63;
    At[dk * 65 + d] = Asm[(size_t)th * 4096 + e];
  }
  for (int e = tid; e < 4096; e += 256) {
    const int fl = e >> 6, dk = e & 63;
    WoSh[e] = Wo[(size_t)(f0 + fl) * 1024 + h * 64 + dk];
  }
  __syncthreads();
  const int d = tid & 63;
  const int fsub = tid >> 6;  // 0..3
#pragma unroll 4
  for (int it = 0; it < 16; ++it) {
    const int fl = it * 4 + fsub;
    float s = 0.f;
#pragma unroll
    for (int dk4 = 0; dk4 < 16; ++dk4) {
      const float4 wv = *(const float4*)&WoSh[fl * 64 + dk4 * 4];
      s += At[(dk4 * 4 + 0) * 65 + d] * wv.x + At[(dk4 * 4 + 1) * 65 + d] * wv.y +
           At[(dk4 * 4 + 2) * 65 + d] * wv.z + At[(dk4 * 4 + 3) * 65 + d] * wv.w;
    }
    Gt[(size_t)(f0 + fl) * 2048 + t * 1024 + h * 64 + d] = f2bf(s);
  }
}

// ---- c0[f] = bo[f] + sum_j bc[j&63]*Wo[f][j]; one wave per f ----
__global__ void make_c0(const float* __restrict__ bc, const float* __restrict__ bo,
                        const float* __restrict__ Wo, float* __restrict__ c0) {
  const int f = blockIdx.x * 4 + (threadIdx.x >> 6);
  const int lane = threadIdx.x & 63;
  const float bcl = bc[lane];
  float s = 0.f;
  for (int j = lane; j < 1024; j += 64) s += bcl * Wo[(size_t)f * 1024 + j];
#pragma unroll
  for (int off = 32; off; off >>= 1) s += __shfl_xor(s, off);
  if (lane == 0) c0[f] = s + bo[f];
}

extern "C" void kernel_launch(void* const* d_in, const int* in_sizes, int n_in,
                              void* d_out, int out_size, void* d_ws, size_t ws_size,
                              hipStream_t stream) {
  const float* query = (const float*)d_in[0];
  const float* key_  = (const float*)d_in[1];
  const float* Wq = (const float*)d_in[4];
  const float* bq = (const float*)d_in[5];
  const float* Wk = (const float*)d_in[6];
  const float* bk = (const float*)d_in[7];
  const float* We = (const float*)d_in[10];
  const float* Wr = (const float*)d_in[11];
  const float* Wc = (const float*)d_in[13];
  const float* bc = (const float*)d_in[14];
  const float* Wo = (const float*)d_in[15];
  const float* bo = (const float*)d_in[16];

  // ws layout (max 76.1 MB)
  char* ws = (char*)d_ws;
  unsigned short* qkbf = (unsigned short*)ws;               // 67MB: q/k bf16, later QKn (16384x2048)
  unsigned short* Wbf  = (unsigned short*)(ws + 67108864);  // 4MB: Wq,Wk bf16
  unsigned short* Gt   = (unsigned short*)(ws + 71303168);  // 4MB: G^T (1024x2048 bf16)
  float* partial       = (float*)(ws + 71303168);           // 2MB, OVERLAYS Gt (dead before make_G)
  float* Asm           = (float*)(ws + 75497472);           // 512KB
  float* c0            = (float*)(ws + 76021760);           // 4KB

  unsigned short* proj = (unsigned short*)d_out;  // d_out as scratch for bf16 projections

  // 1) fp32 -> bf16
  cvt_bf16<<<16384, 256, 0, stream>>>(query, qkbf, 4194304);
  cvt_bf16<<<16384, 256, 0, stream>>>(key_, qkbf + 16777216, 4194304);
  cvt_bf16<<<1024, 256, 0, stream>>>(Wq, Wbf, 262144);
  cvt_bf16<<<1024, 256, 0, stream>>>(Wk, Wbf + 1048576, 262144);

  // 2) q+k projections merged: M=32768 (rows 0..16383 q w/ Wq, 16384.. k w/ Wk)
  gemm8p<1><<<512, 512, 0, stream>>>(qkbf, Wbf, Wbf + 1048576, bq, bk, proj,
                                     32768, 1024, 1024, 16384);

  // 3) causal running mean + l2norm + pack into QKn
  scan_partial<<<dim3(2, 64, 4), 256, 0, stream>>>(proj, partial);
  scan_apply<<<dim3(2, 64, 4), 256, 0, stream>>>(proj, partial, qkbf);

  // 4) fold We/Wr/Wc/Wo into G (after scan: partial dead, Gt region free)
  make_A<<<32, 256, 0, stream>>>(We, Wr, Wc, Asm);
  make_G<<<dim3(32, 16), 256, 0, stream>>>(Asm, Wo, Gt);
  make_c0<<<256, 256, 0, stream>>>(bc, bo, Wo, c0);

  // 5) out = QKn @ Gt^T + c0  (M=16384, N=1024, K=2048), fp32 out
  gemm8p<0><<<256, 512, 0, stream>>>(qkbf, Gt, Gt, c0, c0, (float*)d_out,
                                     16384, 1024, 2048, 16384 * 2);
}